// Round 7
// baseline (225.043 us; speedup 1.0000x reference)
//
#include <hip/hip_runtime.h>
#include <cstddef>
#include <cstdint>

// x (16,4096,256) fp32, kernels (512,256) fp32, out (16,4096,256) fp32
#define BSZ 16
#define PN  4096
#define DD  256
#define CC  512
#define TP  128
#define TC  128
#define NPT (PN / TP)    // 32 position tiles
#define NKC 8            // 8 K-chunks of 32

typedef short bf16x8 __attribute__((ext_vector_type(8)));
typedef float f32x4  __attribute__((ext_vector_type(4)));

struct Top2 { float v1, v2; int i1, i2; };

// larger value wins; tie -> smaller index (jnp.argmax first-occurrence)
__device__ __forceinline__ void t2_insert(Top2& t, float v, int i) {
  if (v > t.v1 || (v == t.v1 && i < t.i1)) {
    t.v2 = t.v1; t.i2 = t.i1; t.v1 = v; t.i1 = i;
  } else if (v > t.v2 || (v == t.v2 && i < t.i2)) {
    t.v2 = v; t.i2 = i;
  }
}

// split float4 -> packed bf16 hi (truncate) + bf16 lo (truncate of exact residual)
__device__ __forceinline__ void split4(float4 v, uint2& hp, uint2& lp) {
  uint32_t u0 = __float_as_uint(v.x), u1 = __float_as_uint(v.y),
           u2 = __float_as_uint(v.z), u3 = __float_as_uint(v.w);
  float l0 = v.x - __uint_as_float(u0 & 0xffff0000u);
  float l1 = v.y - __uint_as_float(u1 & 0xffff0000u);
  float l2 = v.z - __uint_as_float(u2 & 0xffff0000u);
  float l3 = v.w - __uint_as_float(u3 & 0xffff0000u);
  hp.x = __builtin_amdgcn_perm(u1, u0, 0x07060302u);
  hp.y = __builtin_amdgcn_perm(u3, u2, 0x07060302u);
  lp.x = __builtin_amdgcn_perm(__float_as_uint(l1), __float_as_uint(l0), 0x07060302u);
  lp.y = __builtin_amdgcn_perm(__float_as_uint(l3), __float_as_uint(l2), 0x07060302u);
}

// ---------------------------------------------------------------------------
// kernels (512x256) -> bf16 hi/lo in MFMA-fragment slot order.
// Chunk (ct,kc) = 16 KB: hi[512 slots*16B] | lo[...]; slot s = fp*64+kg*16+lr
// holds channel row fp*16+lr, k = kc*32 + kg*8 .. +8.  With this layout a
// wave's B-fragment load is a single contiguous 1-KB global_load_dwordx4.
// ---------------------------------------------------------------------------
__global__ __launch_bounds__(256) void convert_k_kernel(
    const float* __restrict__ kern, uint32_t* __restrict__ ks) {
  const int kc = blockIdx.x, ct = blockIdx.y;
  const size_t chunk = ((size_t)ct * NKC + kc) * 4096;
#pragma unroll
  for (int s0 = 0; s0 < 2; s0++) {
    int s  = threadIdx.x + s0 * 256;
    int fp = s >> 6, kg = (s >> 4) & 3, lr = s & 15;
    int r  = fp * 16 + lr, k0 = kg * 8;
    const float* src = kern + ((size_t)ct * TC + r) * DD + kc * 32 + k0;
    float4 v0 = *(const float4*)src, v1 = *(const float4*)(src + 4);
    uint2 h0, l0, h1, l1; split4(v0, h0, l0); split4(v1, h1, l1);
    *(uint4*)&ks[chunk + (size_t)s * 4]        = make_uint4(h0.x, h0.y, h1.x, h1.y);
    *(uint4*)&ks[chunk + 2048 + (size_t)s * 4] = make_uint4(l0.x, l0.y, l1.x, l1.y);
  }
}

// ---------------------------------------------------------------------------
// Score GEMM: 128p x 128c per block, split-bf16 3-MFMA, fused top-2.
// NO LDS / NO barriers in the K-loop: A and B fragments are loaded straight
// into registers (A fp32 from x, split in-register; B pre-permuted in ks so
// each frag is one contiguous 1-KB wave load). A is prefetched one chunk
// ahead. Block id swizzled so the 4 ct-blocks of one (pt,b) share an XCD.
// ---------------------------------------------------------------------------
__global__ __launch_bounds__(256, 2) void score_kernel(
    const float* __restrict__ x, const uint32_t* __restrict__ ks,
    float2* __restrict__ pv2, uint32_t* __restrict__ pix) {

  __shared__ __align__(16) float4 scratch[8 * TC];   // 4 KB, epilogue only

  // swizzle: id = sg*32 + ct*8 + (pb&7), pb = (sg<<3)|(pb&7)
  const int id = blockIdx.x;
  const int ct = (id >> 3) & 3;
  const int pb = ((id >> 5) << 3) | (id & 7);   // 0..511
  const int pt = pb & 31;
  const int b  = pb >> 5;

  const int tid  = threadIdx.x;
  const int lane = tid & 63, wave = tid >> 6;
  const int wr = wave >> 1, wc = wave & 1;
  const int lr = lane & 15, kg = lane >> 4;

  // A: row = pt*128 + wr*64 + fp*16 + lr; bytes kc*128 + kg*32 + h*16
  const char* abase = (const char*)x
      + (size_t)(b * PN + pt * TP + wr * 64 + lr) * (DD * 4) + kg * 32;
  // B: chunk (ct*8+kc)*16KB; frag offset (wc*4+fc)*1024 + lane*16; lo +8192
  const char* bbase = (const char*)ks + (size_t)ct * NKC * 16384
      + wc * 4096 + lane * 16;

  f32x4 acc[4][4];
#pragma unroll
  for (int i = 0; i < 4; i++)
#pragma unroll
    for (int j = 0; j < 4; j++) acc[i][j] = (f32x4)0.f;

  float4 a_cur[4][2], a_nxt[4][2];
#pragma unroll
  for (int fp = 0; fp < 4; fp++) {
    a_cur[fp][0] = *(const float4*)(abase + fp * 16384);
    a_cur[fp][1] = *(const float4*)(abase + fp * 16384 + 16);
  }

  for (int kc = 0; kc < NKC; kc++) {
    if (kc + 1 < NKC) {
#pragma unroll
      for (int fp = 0; fp < 4; fp++) {
        a_nxt[fp][0] = *(const float4*)(abase + fp * 16384 + (kc + 1) * 128);
        a_nxt[fp][1] = *(const float4*)(abase + fp * 16384 + (kc + 1) * 128 + 16);
      }
    }
    // B fragments for this chunk (L2-hot, 1-KB contiguous per load)
    bf16x8 Bh[4], Bl[4];
#pragma unroll
    for (int fc = 0; fc < 4; fc++) {
      Bh[fc] = *(const bf16x8*)(bbase + kc * 16384 + fc * 1024);
      Bl[fc] = *(const bf16x8*)(bbase + kc * 16384 + fc * 1024 + 8192);
    }
    // split A in-register
    bf16x8 Ah[4], Al[4];
#pragma unroll
    for (int fp = 0; fp < 4; fp++) {
      uint2 h0, l0, h1, l1;
      split4(a_cur[fp][0], h0, l0);
      split4(a_cur[fp][1], h1, l1);
      uint4 hh = make_uint4(h0.x, h0.y, h1.x, h1.y);
      uint4 ll = make_uint4(l0.x, l0.y, l1.x, l1.y);
      Ah[fp] = *(bf16x8*)&hh;
      Al[fp] = *(bf16x8*)&ll;
    }
#pragma unroll
    for (int fc = 0; fc < 4; fc++)
#pragma unroll
      for (int fp = 0; fp < 4; fp++) {
        acc[fp][fc] = __builtin_amdgcn_mfma_f32_16x16x32_bf16(Ah[fp], Bh[fc], acc[fp][fc], 0, 0, 0);
        acc[fp][fc] = __builtin_amdgcn_mfma_f32_16x16x32_bf16(Ah[fp], Bl[fc], acc[fp][fc], 0, 0, 0);
        acc[fp][fc] = __builtin_amdgcn_mfma_f32_16x16x32_bf16(Al[fp], Bh[fc], acc[fp][fc], 0, 0, 0);
      }
#pragma unroll
    for (int fp = 0; fp < 4; fp++) {
      a_cur[fp][0] = a_nxt[fp][0];
      a_cur[fp][1] = a_nxt[fp][1];
    }
  }

  // relu + per-lane top2 per column (C layout: col=lane&15, row=kg*4+reg)
  const int slot = wr * 4 + kg;
#pragma unroll
  for (int fc = 0; fc < 4; fc++) {
    Top2 t; t.v1 = -1.f; t.v2 = -1.f; t.i1 = 0x7fffffff; t.i2 = 0x7fffffff;
#pragma unroll
    for (int fp = 0; fp < 4; fp++)
#pragma unroll
      for (int r = 0; r < 4; r++) {
        float v = acc[fp][fc][r]; v = v > 0.f ? v : 0.f;
        t2_insert(t, v, wr * 64 + fp * 16 + kg * 4 + r);
      }
    int c_local = wc * 64 + fc * 16 + lr;
    scratch[slot * TC + c_local] =
        make_float4(t.v1, __int_as_float(t.i1), t.v2, __int_as_float(t.i2));
  }
  __syncthreads();

  if (tid < TC) {
    Top2 t; t.v1 = -1.f; t.v2 = -1.f; t.i1 = 0x7fffffff; t.i2 = 0x7fffffff;
#pragma unroll
    for (int s = 0; s < 8; s++) {
      float4 e = scratch[s * TC + tid];
      t2_insert(t, e.x, __float_as_int(e.y));
      t2_insert(t, e.z, __float_as_int(e.w));
    }
    int c = ct * TC + tid;
    size_t o = ((size_t)b * CC + c) * NPT + pt;
    uint32_t p1 = (uint32_t)(pt * TP + t.i1);
    uint32_t p2 = (uint32_t)(pt * TP + t.i2);
    pv2[o] = make_float2(t.v1, t.v2);
    pix[o] = (p1 << 16) | (p2 & 0xffffu);
  }
}

// ---------------------------------------------------------------------------
// Per-(b,c): merge 32 tile top-2s; eps-guarded winner; exact fp32 rescue of
// near-ties. 4 channels per block (one per wave). Writes winner[b][c].
// ---------------------------------------------------------------------------
__global__ __launch_bounds__(256) void reduce_winner_kernel(
    const float2* __restrict__ pv2, const uint32_t* __restrict__ pix,
    const float* __restrict__ x, const float* __restrict__ kern,
    int* __restrict__ winner) {
  const int c = blockIdx.x * 4 + (threadIdx.x >> 6);
  const int b = blockIdx.y;
  const int l = threadIdx.x & 63;

  Top2 t; t.v1 = -1.f; t.v2 = -1.f; t.i1 = 0x7fffffff; t.i2 = 0x7fffffff;
  if (l < NPT) {
    size_t o = ((size_t)b * CC + c) * NPT + l;
    float2 v = pv2[o]; uint32_t ii = pix[o];
    t.v1 = v.x; t.v2 = v.y; t.i1 = (int)(ii >> 16); t.i2 = (int)(ii & 0xffffu);
  }
#pragma unroll
  for (int m = 1; m < 64; m <<= 1) {
    float uv1 = __shfl_xor(t.v1, m, 64);
    int   ui1 = __shfl_xor(t.i1, m, 64);
    float uv2 = __shfl_xor(t.v2, m, 64);
    int   ui2 = __shfl_xor(t.i2, m, 64);
    t2_insert(t, uv1, ui1);
    t2_insert(t, uv2, ui2);
  }

  int win = t.i1;
  if (t.v1 - t.v2 <= 1e-4f * t.v1 + 1e-5f) {   // rare near-tie: exact fp32
    const float4* x1 = (const float4*)(x + ((size_t)b * PN + t.i1) * DD);
    const float4* x2 = (const float4*)(x + ((size_t)b * PN + t.i2) * DD);
    const float4* kc = (const float4*)(kern + (size_t)c * DD);
    float4 a1 = x1[l], a2 = x2[l], k4 = kc[l];
    float s1 = a1.x * k4.x + a1.y * k4.y + a1.z * k4.z + a1.w * k4.w;
    float s2 = a2.x * k4.x + a2.y * k4.y + a2.z * k4.z + a2.w * k4.w;
#pragma unroll
    for (int m = 1; m < 64; m <<= 1) {
      s1 += __shfl_xor(s1, m, 64);
      s2 += __shfl_xor(s2, m, 64);
    }
    s1 = fmaxf(s1, 0.f); s2 = fmaxf(s2, 0.f);
    if (s2 > s1 || (s2 == s1 && t.i2 < t.i1)) win = t.i2;
  }
  if (l == 0) winner[(size_t)b * CC + c] = win;
}

// ---------------------------------------------------------------------------
// 16 positions per block (4 waves x 4 positions); winner row staged in LDS
// once per block. Each wave ballots matching channels, sums kernel rows,
// writes its rows. Full coverage -> no memset, no atomics.
// ---------------------------------------------------------------------------
__global__ __launch_bounds__(256) void write_out_kernel(
    const int* __restrict__ winner, const float* __restrict__ kern,
    float4* __restrict__ out) {
  __shared__ __align__(16) int wrow[CC];
  const int b = blockIdx.y;
  const int tid = threadIdx.x, lane = tid & 63, w = tid >> 6;

  *(int2*)&wrow[tid * 2] = *(const int2*)&winner[(size_t)b * CC + tid * 2];
  __syncthreads();

  int4 w0 = *(const int4*)&wrow[lane * 8];
  int4 w1 = *(const int4*)&wrow[lane * 8 + 4];
  int wv[8] = {w0.x, w0.y, w0.z, w0.w, w1.x, w1.y, w1.z, w1.w};

#pragma unroll
  for (int pi = 0; pi < 4; pi++) {
    const int p = blockIdx.x * 16 + w * 4 + pi;
    float4 acc = make_float4(0.f, 0.f, 0.f, 0.f);
#pragma unroll
    for (int j = 0; j < 8; j++) {
      unsigned long long m = __ballot(wv[j] == p);
      while (m) {
        int bit = __ffsll((long long)m) - 1; m &= m - 1;
        int c = bit * 8 + j;                    // wave-uniform
        float4 kv = ((const float4*)(kern + (size_t)c * DD))[lane];
        acc.x += kv.x; acc.y += kv.y; acc.z += kv.z; acc.w += kv.w;
      }
    }
    out[((size_t)b * PN + p) * 64 + lane] = acc;
  }
}

// ---------------------------------------------------------------------------
extern "C" void kernel_launch(void* const* d_in, const int* in_sizes, int n_in,
                              void* d_out, int out_size, void* d_ws, size_t ws_size,
                              hipStream_t stream) {
  const float* x    = (const float*)d_in[0];   // (16,4096,256)
  const float* kern = (const float*)d_in[1];   // (512,256)
  float* out = (float*)d_out;

  // ws: pv2 2 MB | pix 1 MB | ks 512 KB | winner 32 KB
  char* ws = (char*)d_ws;
  float2*   pv2 = (float2*)ws;
  uint32_t* pix = (uint32_t*)(ws + (size_t)BSZ * CC * NPT * sizeof(float2));
  uint32_t* ks  = (uint32_t*)(ws + 3u * 1024 * 1024);
  int*      win = (int*)(ws + 3u * 1024 * 1024 + 512u * 1024);

  convert_k_kernel<<<dim3(NKC, CC / TC), 256, 0, stream>>>(kern, ks);

  score_kernel<<<dim3(4 * NPT * BSZ), 256, 0, stream>>>(x, ks, pv2, pix);

  reduce_winner_kernel<<<dim3(CC / 4, BSZ), 256, 0, stream>>>(pv2, pix, x, kern, win);

  write_out_kernel<<<dim3(PN / 16, BSZ), 256, 0, stream>>>(win, kern, (float4*)out);
}